// Round 12
// baseline (784.784 us; speedup 1.0000x reference)
//
#include <hip/hip_runtime.h>

typedef unsigned short u16;
typedef unsigned int   u32;
typedef __attribute__((ext_vector_type(8))) __bf16 bf16x8;
typedef __attribute__((ext_vector_type(4))) float   f32x4;

// ---------------- dims ----------------
#define NT   16384      // tokens = 4*4096
#define DD   1024
#define FFD  4096

// ---------------- ws layout (bytes), total ~152 MB ----------------
#define SREG  ((size_t)33554432)            // 32MB = 16384*1024*2
#define S1O   ((size_t)0)
#define S2O   (SREG)
#define S3O   (2*SREG)
#define S4O   (3*SREG)
#define O_WQ  (4*SREG)                      // 134,217,728
#define O_WK  (O_WQ + (size_t)2097152)
#define O_W1  (O_WK + (size_t)2097152)
#define O_W2  (O_W1 + (size_t)8388608)
#define O_FWD (O_W2 + (size_t)8388608)
#define O_INV (O_FWD + (size_t)2097152)
#define O_SF  (O_INV + (size_t)2097152)
// end = O_SF + 16384 = 159,399,936 bytes

// ---------------- helpers ----------------
__device__ __forceinline__ float b2f(u16 h) {
    u32 u = ((u32)h) << 16;
    return __uint_as_float(u);
}
__device__ __forceinline__ u16 f2b(float f) {  // RNE
    u32 u = __float_as_uint(f);
    u32 r = (u + 0x7FFFu + ((u >> 16) & 1u)) >> 16;
    return (u16)r;
}

__device__ __forceinline__ void ld16(const u16* g, u16* l) {
    __builtin_amdgcn_global_load_lds(
        (const __attribute__((address_space(1))) void*)g,
        (__attribute__((address_space(3))) void*)l, 16, 0, 0);
}

__device__ __forceinline__ void block_red2(float& a, float& b, float* red, int tid) {
#pragma unroll
    for (int off = 32; off; off >>= 1) {
        a += __shfl_down(a, off, 64);
        b += __shfl_down(b, off, 64);
    }
    int w = tid >> 6;
    if ((tid & 63) == 0) { red[w] = a; red[4 + w] = b; }
    __syncthreads();
    a = red[0] + red[1] + red[2] + red[3];
    b = red[4] + red[5] + red[6] + red[7];
}

// ---------------- consolidated prep kernel ----------------
// One range-partitioned grid replaces: zero_sf + 5 casts + gen_fwd + gen_inv.
//   [0, 4194304)                 x  (f32->bf16) -> S1
//   [4194304, 4456448)           Wq -> wq16
//   [4456448, 4718592)           Wk -> wk16
//   [4718592, 5767168)           W1 -> w116
//   [5767168, 6815744)           W2 -> w216
//   [6815744, 7077888)           gen fwdP (4 elems/item)
//   [7077888, 7340032)           gen invP (4 elems/item)
//   [7340032, 7341056)           Sf zero (float4)
#define PREP_ITEMS 7341056
#define PREP_GRID  28676          // * 256 = 7,341,056

__device__ __forceinline__ void cast4(const float* __restrict__ s, u16* __restrict__ d, int i) {
    float4 v = ((const float4*)s)[i];
    ushort4 o;
    o.x = f2b(v.x); o.y = f2b(v.y); o.z = f2b(v.z); o.w = f2b(v.w);
    ((ushort4*)d)[i] = o;
}

__global__ void prep_k(const float* __restrict__ x,  const float* __restrict__ Wq,
                       const float* __restrict__ Wk, const float* __restrict__ W1,
                       const float* __restrict__ W2,
                       u16* __restrict__ S1,   u16* __restrict__ wq16,
                       u16* __restrict__ wk16, u16* __restrict__ w116,
                       u16* __restrict__ w216, u16* __restrict__ fwdP,
                       u16* __restrict__ invP, float* __restrict__ Sf) {
    int i = blockIdx.x * 256 + threadIdx.x;
    if (i < 4194304) {
        cast4(x, S1, i);
    } else if (i < 4456448) {
        cast4(Wq, wq16, i - 4194304);
    } else if (i < 4718592) {
        cast4(Wk, wk16, i - 4456448);
    } else if (i < 5767168) {
        cast4(W1, w116, i - 4718592);
    } else if (i < 6815744) {
        cast4(W2, w216, i - 5767168);
    } else if (i < 7077888) {
        // packed-spectrum forward DFT matrix (bf16), 4 elems per item.
        // col0 = Re F_0; odd n -> Re F_{(n+1)/2}; even n>0 -> Im F_{n/2};
        // numpy rfft: F_f = sum_k v_k e^{-2pi i f k /1024}.
        int g4 = i - 6815744;
        int idx = g4 << 2;
        int n = idx >> 10, k0 = idx & 1023;
        int f  = (n == 0) ? 0 : ((n & 1) ? ((n + 1) >> 1) : (n >> 1));
        bool re = (n == 0) || (n & 1);
        ushort4 o;
        u16* po = (u16*)&o;
#pragma unroll
        for (int j = 0; j < 4; ++j) {
            int r = (f * (k0 + j)) & 1023;
            float ang = (float)r * 6.1359233e-3f;   // 2*pi/1024
            float v = re ? __cosf(ang) : -__sinf(ang);
            po[j] = f2b(v);
        }
        ((ushort4*)fwdP)[g4] = o;
    } else if (i < 7340032) {
        // irfft: v_d = (1/1024)[F_0 + (-1)^d Re F_512
        //               + 2*sum_{f=1}^{511}(Re F_f cos - Im F_f sin)]
        int g4 = i - 7077888;
        int idx = g4 << 2;
        int d = idx >> 10, n0 = idx & 1023;
        ushort4 o;
        u16* po = (u16*)&o;
#pragma unroll
        for (int j = 0; j < 4; ++j) {
            int n = n0 + j;
            int f  = (n == 0) ? 0 : ((n & 1) ? ((n + 1) >> 1) : (n >> 1));
            bool re = (n == 0) || (n & 1);
            int r = (f * d) & 1023;
            float ang = (float)r * 6.1359233e-3f;
            float c = (f == 0 || f == 512) ? (1.0f / 1024.0f) : (2.0f / 1024.0f);
            float v = re ? c * __cosf(ang) : -c * __sinf(ang);
            po[j] = f2b(v);
        }
        ((ushort4*)invP)[g4] = o;
    } else {
        int j = i - 7340032;   // < 1024 float4s = 4096 floats
        ((float4*)Sf)[j] = float4{0.f, 0.f, 0.f, 0.f};
    }
}

// ---------------- GEMM: C[m,n] = sum_k A[m,k]*B[n,k] ----------------
// m97 structure + XCD swizzle + XOR-swizzled LDS (bank-conflict-free, staged
// by permuting each lane's GLOBAL chunk so global_load_lds's fixed lane->slot
// mapping still lands contiguously; slot (r,c) holds global chunk c^(r&7)).
// HARNESS-PROVEN; MfmaUtil ~36% = this structure's ceiling.
// DO NOT RESTRUCTURE (R2/R3/R4: 256^2/8-phase ports all 96-102us vs 81us).
// DO NOT DROP BELOW ~3 BLOCKS/CU (R9: 512-block W2 = 2/CU cost ~55us).
// z-BATCHING PROVEN for operand-sharing GEMMs (R10: b3 = 32.9us/GEMM,
// MfmaUtil 48%, FETCH 78MB vs 3x87 — tail + HBM-refetch amortized).
#define BM 128
#define BN 128
#define BK 64
#define EPI_BF16            0  // bf16 store
#define EPI_BIAS_BF16       1  // bf16 store, + bias[n]
#define EPI_BIAS_RELU_BF16  2  // bf16 store, + bias[n], relu
#define EPI_BIAS_ADDB_F32   3  // f32 store,  + bias[n] + bf16 residual addp16[off]
#define EPI_ADD_F32         4  // f32 store,  + existing f32 Cout[off]

template <int EPI>
__device__ __forceinline__ void gemm_body(
    const u16* __restrict__ A, const u16* __restrict__ B, void* __restrict__ Cout,
    const float* __restrict__ bias, const u16* __restrict__ addp16,
    int K, int lda, int ldb, int ldc)
{
    __shared__ __align__(16) u16 As[BM * BK];
    __shared__ __align__(16) u16 Bs[BN * BK];
    const int tid = threadIdx.x;

    // XCD-aware swizzle over the x/y grid only (z-batched slices each keep
    // their own contiguous-band mapping; per-slice nb % 8 == 0 holds).
    int m0, n0;
    {
        const int id = blockIdx.y * gridDim.x + blockIdx.x;
        const int nb = gridDim.x * gridDim.y;
        if ((nb & 7) == 0) {
            const int per = nb >> 3;
            const int t = (id & 7) * per + (id >> 3);
            n0 = (t % gridDim.x) * BN;
            m0 = (t / gridDim.x) * BM;
        } else {
            n0 = blockIdx.x * BN;
            m0 = blockIdx.y * BM;
        }
    }

    const int w = tid >> 6, l = tid & 63;
    const int wm = (w >> 1) << 6, wn = (w & 1) << 6;
    const int tm = l & 15, quad = l >> 4;
    const int sw = (tm & 7) << 3;            // read-side XOR swizzle (in u16 elems)

    f32x4 acc[4][4] = {};

    const int sr = tid >> 3;
    const int sc = ((tid & 7) ^ (sr & 7)) << 3;   // staged-side swizzled global chunk
    const u16* Ag = A + (size_t)(m0 + sr) * lda;
    const u16* Bg = B + (size_t)(n0 + sr) * ldb;
    u16* Asl = As + tid * 8;
    u16* Bsl = Bs + tid * 8;
    const size_t a32 = (size_t)32 * lda, b32 = (size_t)32 * ldb;

    for (int k0 = 0; k0 < K; k0 += BK) {
#pragma unroll
        for (int i = 0; i < 4; ++i) {
            ld16(Ag + (size_t)i * a32 + k0 + sc, Asl + i * 2048);
            ld16(Bg + (size_t)i * b32 + k0 + sc, Bsl + i * 2048);
        }
        __syncthreads();
#pragma unroll
        for (int kk = 0; kk < BK; kk += 32) {
            bf16x8 af[4], bfr[4];
#pragma unroll
            for (int i = 0; i < 4; ++i)
                af[i] = *(const bf16x8*)(const void*)(As + (wm + i * 16 + tm) * BK + ((((kk >> 3) + quad) << 3) ^ sw));
#pragma unroll
            for (int j = 0; j < 4; ++j)
                bfr[j] = *(const bf16x8*)(const void*)(Bs + (wn + j * 16 + tm) * BK + ((((kk >> 3) + quad) << 3) ^ sw));
#pragma unroll
            for (int i = 0; i < 4; ++i)
#pragma unroll
                for (int j = 0; j < 4; ++j)
                    acc[i][j] = __builtin_amdgcn_mfma_f32_16x16x32_bf16(af[i], bfr[j], acc[i][j], 0, 0, 0);
        }
        __syncthreads();
    }

    // C/D layout: col=lane&15, row=quad*4+reg (m89/m91-verified)
#pragma unroll
    for (int i = 0; i < 4; ++i) {
        const int gmb = m0 + wm + i * 16 + quad * 4;
#pragma unroll
        for (int j = 0; j < 4; ++j) {
            const int gn = n0 + wn + j * 16 + tm;
            float bv = 0.f;
            if (EPI == EPI_BIAS_BF16 || EPI == EPI_BIAS_RELU_BF16 || EPI == EPI_BIAS_ADDB_F32)
                bv = bias[gn];
#pragma unroll
            for (int r = 0; r < 4; ++r) {
                size_t off = (size_t)(gmb + r) * ldc + gn;
                float v = acc[i][j][r] + bv;
                if (EPI == EPI_BIAS_ADDB_F32) v += b2f(addp16[off]);
                if (EPI == EPI_ADD_F32)       v += ((const float*)Cout)[off];
                if (EPI == EPI_BIAS_RELU_BF16) v = fmaxf(v, 0.f);
                if (EPI == EPI_BF16 || EPI == EPI_BIAS_BF16 || EPI == EPI_BIAS_RELU_BF16)
                    ((u16*)Cout)[off] = f2b(v);
                else
                    ((float*)Cout)[off] = v;
            }
        }
    }
}

template <int EPI>
__global__ __launch_bounds__(256, 3) void gemm_bt_k(
    const u16* __restrict__ A, const u16* __restrict__ B, void* __restrict__ Cout,
    const float* __restrict__ bias, const u16* __restrict__ addp16,
    int K, int lda, int ldb, int ldc)
{
    gemm_body<EPI>(A, B, Cout, bias, addp16, K, lda, ldb, ldc);
}

// z-batched: 3 GEMMs sharing B (forward DFTs), z selects A and C.
// R10-proven: 98.8us total (32.9/GEMM), MfmaUtil 48%, FETCH 78MB.
__global__ __launch_bounds__(256, 3) void gemm_b3_k(
    const u16* __restrict__ A0, const u16* __restrict__ A1, const u16* __restrict__ A2,
    const u16* __restrict__ B,
    u16* __restrict__ C0, u16* __restrict__ C1, u16* __restrict__ C2,
    int K, int lda, int ldb, int ldc)
{
    const int z = blockIdx.z;
    const u16* A = (z == 0) ? A0 : ((z == 1) ? A1 : A2);
    u16*       C = (z == 0) ? C0 : ((z == 1) ? C1 : C2);
    gemm_body<EPI_BF16>(A, B, C, nullptr, nullptr, K, lda, ldb, ldc);
}

// ---------------- LayerNorm bf16 -> bf16 (may be in-place) ----------------
__global__ void ln_bf16_k(const u16* __restrict__ src, u16* __restrict__ dst,
                          const float* __restrict__ g, const float* __restrict__ be) {
    __shared__ float red[8];
    const int t = blockIdx.x, tid = threadIdx.x;
    ushort4 h = ((const ushort4*)(src + (size_t)t * DD))[tid];
    float4 v = { b2f(h.x), b2f(h.y), b2f(h.z), b2f(h.w) };
    float s  = v.x + v.y + v.z + v.w;
    float ss = v.x * v.x + v.y * v.y + v.z * v.z + v.w * v.w;
    block_red2(s, ss, red, tid);
    float mean = s * (1.f / 1024.f);
    float inv  = 1.0f / sqrtf(ss * (1.f / 1024.f) - mean * mean + 1e-5f);
    float4 gv = ((const float4*)g)[tid];
    float4 bv = ((const float4*)be)[tid];
    ushort4 o;
    o.x = f2b((v.x - mean) * inv * gv.x + bv.x);
    o.y = f2b((v.y - mean) * inv * gv.y + bv.y);
    o.z = f2b((v.z - mean) * inv * gv.z + bv.z);
    o.w = f2b((v.w - mean) * inv * gv.w + bv.w);
    ((ushort4*)(dst + (size_t)t * DD))[tid] = o;
}

// fused q/k LayerNorm: one dispatch, two in-place tensors
__global__ void ln2_bf16_k(u16* __restrict__ qb, u16* __restrict__ kb,
                           const float* __restrict__ gq, const float* __restrict__ beq,
                           const float* __restrict__ gk, const float* __restrict__ bek) {
    __shared__ float red[8];
    const int b = blockIdx.x, tid = threadIdx.x;
    u16* io         = (b < NT) ? qb : kb;
    const float* g  = (b < NT) ? gq : gk;
    const float* be = (b < NT) ? beq : bek;
    const int t = (b < NT) ? b : (b - NT);
    ushort4 h = ((const ushort4*)(io + (size_t)t * DD))[tid];
    float4 v = { b2f(h.x), b2f(h.y), b2f(h.z), b2f(h.w) };
    float s  = v.x + v.y + v.z + v.w;
    float ss = v.x * v.x + v.y * v.y + v.z * v.z + v.w * v.w;
    block_red2(s, ss, red, tid);
    float mean = s * (1.f / 1024.f);
    float inv  = 1.0f / sqrtf(ss * (1.f / 1024.f) - mean * mean + 1e-5f);
    float4 gv = ((const float4*)g)[tid];
    float4 bv = ((const float4*)be)[tid];
    ushort4 o;
    o.x = f2b((v.x - mean) * inv * gv.x + bv.x);
    o.y = f2b((v.y - mean) * inv * gv.y + bv.y);
    o.z = f2b((v.z - mean) * inv * gv.z + bv.z);
    o.w = f2b((v.w - mean) * inv * gv.w + bv.w);
    ((ushort4*)(io + (size_t)t * DD))[tid] = o;
}

// ---------------- final LN in place on d_out (f32) ----------------
__global__ void ln_out_k(float* __restrict__ io, const float* __restrict__ g,
                         const float* __restrict__ be) {
    __shared__ float red[8];
    const int t = blockIdx.x, tid = threadIdx.x;
    float4 v = ((const float4*)(io + (size_t)t * DD))[tid];
    float s  = v.x + v.y + v.z + v.w;
    float ss = v.x * v.x + v.y * v.y + v.z * v.z + v.w * v.w;
    block_red2(s, ss, red, tid);
    float mean = s * (1.f / 1024.f);
    float inv  = 1.0f / sqrtf(ss * (1.f / 1024.f) - mean * mean + 1e-5f);
    float4 gv = ((const float4*)g)[tid];
    float4 bv = ((const float4*)be)[tid];
    float4 o;
    o.x = (v.x - mean) * inv * gv.x + bv.x;
    o.y = (v.y - mean) * inv * gv.y + bv.y;
    o.z = (v.z - mean) * inv * gv.z + bv.z;
    o.w = (v.w - mean) * inv * gv.w + bv.w;
    ((float4*)(io + (size_t)t * DD))[tid] = o;
}

// ---------------- pw1: Sf[b] += Kf .* Xf  (packed spectra) ----------------
// PW1_TOK=16 (R5-proven): 1024 blocks = 4 waves/SIMD TLP. TOK=64 (R8)
// collapsed TLP to 1 wave/SIMD and regressed ~18us — latency-bound, not
// atomic-bound. Keep 16.
#define PW1_TOK 16
__global__ void pw1_k(const u16* __restrict__ FTx, const u16* __restrict__ FTk,
                      float* __restrict__ Sf) {
    const int tid = threadIdx.x;
    const int t0 = blockIdx.x * PW1_TOK;
    const int b = t0 >> 12;
    float a0 = 0.f;
    float ar1 = 0.f, ai1 = 0.f;
    float ar2 = 0.f, ai2 = 0.f;
    const int f1 = tid + 1, f2 = tid + 257;
    for (int it = 0; it < PW1_TOK; ++it) {
        const size_t ro = (size_t)(t0 + it) * DD;
        const u16* rx = FTx + ro;
        const u16* rk = FTk + ro;
        if (tid == 0) a0 += b2f(rk[0]) * b2f(rx[0]);
        {
            float xr = b2f(rx[2 * f1 - 1]), xi = b2f(rx[2 * f1]);
            float kr = b2f(rk[2 * f1 - 1]), ki = b2f(rk[2 * f1]);
            ar1 += kr * xr - ki * xi;
            ai1 += kr * xi + ki * xr;
        }
        if (f2 < 512) {
            float xr = b2f(rx[2 * f2 - 1]), xi = b2f(rx[2 * f2]);
            float kr = b2f(rk[2 * f2 - 1]), ki = b2f(rk[2 * f2]);
            ar2 += kr * xr - ki * xi;
            ai2 += kr * xi + ki * xr;
        } else {
            ar2 += b2f(rk[1023]) * b2f(rx[1023]);
        }
    }
    float* sb = Sf + (size_t)b * DD;
    if (tid == 0) atomicAdd(&sb[0], a0);
    atomicAdd(&sb[2 * f1 - 1], ar1);
    atomicAdd(&sb[2 * f1],     ai1);
    if (f2 < 512) {
        atomicAdd(&sb[2 * f2 - 1], ar2);
        atomicAdd(&sb[2 * f2],     ai2);
    } else {
        atomicAdd(&sb[1023], ar2);
    }
}

// ---------------- pw2: G = Xf + Kf.*Xf + Sf.*conj(Qf), in-place over FTx ----------------
__global__ void pw2_k(u16* __restrict__ FTx, const u16* __restrict__ FTk,
                      const u16* __restrict__ FTq, const float* __restrict__ Sf) {
    const int t = blockIdx.x, tid = threadIdx.x;
    const int b = t >> 12;
    const size_t ro = (size_t)t * DD;
    u16* rx = FTx + ro;
    const u16* rk = FTk + ro;
    const u16* rq = FTq + ro;
    const float* sb = Sf + (size_t)b * DD;
    const int f1 = tid + 1, f2 = tid + 257;
    if (tid == 0) {
        float x = b2f(rx[0]), k = b2f(rk[0]), q = b2f(rq[0]);
        rx[0] = f2b(x + k * x + sb[0] * q);
    }
    {
        float xr = b2f(rx[2 * f1 - 1]), xi = b2f(rx[2 * f1]);
        float kr = b2f(rk[2 * f1 - 1]), ki = b2f(rk[2 * f1]);
        float qr = b2f(rq[2 * f1 - 1]), qi = b2f(rq[2 * f1]);
        float sr = sb[2 * f1 - 1], si = sb[2 * f1];
        rx[2 * f1 - 1] = f2b(xr + (kr * xr - ki * xi) + (sr * qr + si * qi));
        rx[2 * f1]     = f2b(xi + (kr * xi + ki * xr) + (si * qr - sr * qi));
    }
    if (f2 < 512) {
        float xr = b2f(rx[2 * f2 - 1]), xi = b2f(rx[2 * f2]);
        float kr = b2f(rk[2 * f2 - 1]), ki = b2f(rk[2 * f2]);
        float qr = b2f(rq[2 * f2 - 1]), qi = b2f(rq[2 * f2]);
        float sr = sb[2 * f2 - 1], si = sb[2 * f2];
        rx[2 * f2 - 1] = f2b(xr + (kr * xr - ki * xi) + (sr * qr + si * qi));
        rx[2 * f2]     = f2b(xi + (kr * xi + ki * xr) + (si * qr - sr * qi));
    } else {
        float x = b2f(rx[1023]), k = b2f(rk[1023]), q = b2f(rq[1023]);
        rx[1023] = f2b(x + k * x + sb[1023] * q);
    }
}

// ---------------- launch ----------------
extern "C" void kernel_launch(void* const* d_in, const int* in_sizes, int n_in,
                              void* d_out, int out_size, void* d_ws, size_t ws_size,
                              hipStream_t stream) {
    const float* x     = (const float*)d_in[0];
    const float* Wq    = (const float*)d_in[1];
    const float* bq    = (const float*)d_in[2];
    const float* gq    = (const float*)d_in[3];
    const float* betaq = (const float*)d_in[4];
    const float* Wk    = (const float*)d_in[5];
    const float* bk    = (const float*)d_in[6];
    const float* gk    = (const float*)d_in[7];
    const float* betak = (const float*)d_in[8];
    const float* g0    = (const float*)d_in[9];
    const float* beta0 = (const float*)d_in[10];
    const float* W1    = (const float*)d_in[11];
    const float* b1    = (const float*)d_in[12];
    const float* W2    = (const float*)d_in[13];
    const float* b2    = (const float*)d_in[14];
    const float* g1    = (const float*)d_in[15];
    const float* beta1 = (const float*)d_in[16];

    char* ws = (char*)d_ws;
    u16* S1 = (u16*)(ws + S1O);   // xb16 -> x1b
    u16* S2 = (u16*)(ws + S2O);   // qb -> T
    u16* S3 = (u16*)(ws + S3O);   // kb -> H chunk (S3..S4)
    u16* S4 = (u16*)(ws + S4O);   // FTx -> G
    u16* wq16 = (u16*)(ws + O_WQ);
    u16* wk16 = (u16*)(ws + O_WK);
    u16* w116 = (u16*)(ws + O_W1);
    u16* w216 = (u16*)(ws + O_W2);
    u16* fwdP = (u16*)(ws + O_FWD);
    u16* invP = (u16*)(ws + O_INV);
    float* Sf = (float*)(ws + O_SF);
    float* out = (float*)d_out;
    u16* O16 = (u16*)d_out;       // d_out as bf16 scratch for FTk/FTq
    u16* O16h = O16 + (size_t)16777216;   // +32MB

    // consts: single consolidated prep dispatch (casts + DFT gens + Sf zero)
    prep_k<<<PREP_GRID, 256, 0, stream>>>(x, Wq, Wk, W1, W2,
                                          S1, wq16, wk16, w116, w216,
                                          fwdP, invP, Sf);

    // q/k projections as two separate dispatches (R5-proven; isolating
    // whether R10's z=2 batch was the ~+21us regression), then fused q/k LN
    gemm_bt_k<EPI_BIAS_BF16><<<dim3(8, 128), 256, 0, stream>>>(S1, wq16, S2, bq, nullptr, 1024, 1024, 1024, 1024);
    gemm_bt_k<EPI_BIAS_BF16><<<dim3(8, 128), 256, 0, stream>>>(S1, wk16, S3, bk, nullptr, 1024, 1024, 1024, 1024);
    ln2_bf16_k<<<2 * NT, 256, 0, stream>>>(S2, S3, gq, betaq, gk, betak);

    // forward DFTs batched in one dispatch (R10-proven, 32.9us/GEMM):
    // FTx=S1·Fwd -> S4, FTk=kb·Fwd -> O16, FTq=qb·Fwd -> O16h (d_out as
    // scratch; consumed by pw1/pw2 strictly before W2a overwrites out).
    gemm_b3_k<<<dim3(8, 128, 3), 256, 0, stream>>>(S1, S3, S2, fwdP,
                                                   S4, O16, O16h,
                                                   1024, 1024, 1024, 1024);

    // freq-domain pointwise
    pw1_k<<<NT / PW1_TOK, 256, 0, stream>>>(S4, O16, Sf);
    pw2_k<<<NT, 256, 0, stream>>>(S4, O16, O16h, Sf);   // G in-place over FTx (S4)

    // inverse DFT: T = G @ Inv^T (bf16)
    gemm_bt_k<EPI_BF16><<<dim3(8, 128), 256, 0, stream>>>(S4, invP, S2, nullptr, nullptr, 1024, 1024, 1024, 1024);

    // x1 = LN(T) -> bf16
    ln_bf16_k<<<NT, 256, 0, stream>>>(S2, S1, g0, beta0);

    // FFN in two F-chunks of 2048 (R5-proven; M-chunked W2 at 512 blocks
    // regressed -55us in R9). H chunk lives in S3..S4 (64MB). W2a's full
    // 64MB f32 write also retires the FTk/FTq scratch in d_out.
    gemm_bt_k<EPI_BIAS_RELU_BF16><<<dim3(16, 128), 256, 0, stream>>>(S1, w116, S3, b1, nullptr, 1024, 1024, 1024, 2048);
    gemm_bt_k<EPI_BIAS_ADDB_F32><<<dim3(8, 128), 256, 0, stream>>>(S3, w216, out, b2, S1, 2048, 2048, 4096, 1024);
    gemm_bt_k<EPI_BIAS_RELU_BF16><<<dim3(16, 128), 256, 0, stream>>>(S1, w116 + (size_t)2048 * 1024, S3, b1 + 2048, nullptr, 1024, 1024, 1024, 2048);
    gemm_bt_k<EPI_ADD_F32><<<dim3(8, 128), 256, 0, stream>>>(S3, w216 + 2048, out, nullptr, nullptr, 2048, 2048, 4096, 1024);

    // final LN in place
    ln_out_k<<<NT, 256, 0, stream>>>(out, g1, beta1);

    (void)in_sizes; (void)n_in; (void)out_size; (void)ws_size;
}

// Round 13
// 771.629 us; speedup vs baseline: 1.0170x; 1.0170x over previous
//
#include <hip/hip_runtime.h>

typedef unsigned short u16;
typedef unsigned int   u32;
typedef __attribute__((ext_vector_type(8))) __bf16 bf16x8;
typedef __attribute__((ext_vector_type(4))) float   f32x4;

// ---------------- dims ----------------
#define NT   16384      // tokens = 4*4096
#define DD   1024
#define FFD  4096

// ---------------- ws layout (bytes), total ~152 MB ----------------
#define SREG  ((size_t)33554432)            // 32MB = 16384*1024*2
#define S1O   ((size_t)0)
#define S2O   (SREG)
#define S3O   (2*SREG)
#define S4O   (3*SREG)
#define O_WQ  (4*SREG)                      // 134,217,728
#define O_WK  (O_WQ + (size_t)2097152)
#define O_W1  (O_WK + (size_t)2097152)
#define O_W2  (O_W1 + (size_t)8388608)
#define O_FWD (O_W2 + (size_t)8388608)
#define O_INV (O_FWD + (size_t)2097152)
#define O_SF  (O_INV + (size_t)2097152)
// end = O_SF + 16384 = 159,399,936 bytes

// ---------------- helpers ----------------
__device__ __forceinline__ float b2f(u16 h) {
    u32 u = ((u32)h) << 16;
    return __uint_as_float(u);
}
__device__ __forceinline__ u16 f2b(float f) {  // RNE
    u32 u = __float_as_uint(f);
    u32 r = (u + 0x7FFFu + ((u >> 16) & 1u)) >> 16;
    return (u16)r;
}

__device__ __forceinline__ void ld16(const u16* g, u16* l) {
    __builtin_amdgcn_global_load_lds(
        (const __attribute__((address_space(1))) void*)g,
        (__attribute__((address_space(3))) void*)l, 16, 0, 0);
}

__device__ __forceinline__ void block_red2(float& a, float& b, float* red, int tid) {
#pragma unroll
    for (int off = 32; off; off >>= 1) {
        a += __shfl_down(a, off, 64);
        b += __shfl_down(b, off, 64);
    }
    int w = tid >> 6;
    if ((tid & 63) == 0) { red[w] = a; red[4 + w] = b; }
    __syncthreads();
    a = red[0] + red[1] + red[2] + red[3];
    b = red[4] + red[5] + red[6] + red[7];
}

// ---------------- consolidated prep kernel ----------------
// One range-partitioned grid replaces: zero_sf + 5 casts + gen_fwd + gen_inv.
//   [0, 4194304)                 x  (f32->bf16) -> S1
//   [4194304, 4456448)           Wq -> wq16
//   [4456448, 4718592)           Wk -> wk16
//   [4718592, 5767168)           W1 -> w116
//   [5767168, 6815744)           W2 -> w216
//   [6815744, 7077888)           gen fwdP (4 elems/item)
//   [7077888, 7340032)           gen invP (4 elems/item)
//   [7340032, 7341056)           Sf zero (float4)
#define PREP_ITEMS 7341056
#define PREP_GRID  28676          // * 256 = 7,341,056

__device__ __forceinline__ void cast4(const float* __restrict__ s, u16* __restrict__ d, int i) {
    float4 v = ((const float4*)s)[i];
    ushort4 o;
    o.x = f2b(v.x); o.y = f2b(v.y); o.z = f2b(v.z); o.w = f2b(v.w);
    ((ushort4*)d)[i] = o;
}

__global__ void prep_k(const float* __restrict__ x,  const float* __restrict__ Wq,
                       const float* __restrict__ Wk, const float* __restrict__ W1,
                       const float* __restrict__ W2,
                       u16* __restrict__ S1,   u16* __restrict__ wq16,
                       u16* __restrict__ wk16, u16* __restrict__ w116,
                       u16* __restrict__ w216, u16* __restrict__ fwdP,
                       u16* __restrict__ invP, float* __restrict__ Sf) {
    int i = blockIdx.x * 256 + threadIdx.x;
    if (i < 4194304) {
        cast4(x, S1, i);
    } else if (i < 4456448) {
        cast4(Wq, wq16, i - 4194304);
    } else if (i < 4718592) {
        cast4(Wk, wk16, i - 4456448);
    } else if (i < 5767168) {
        cast4(W1, w116, i - 4718592);
    } else if (i < 6815744) {
        cast4(W2, w216, i - 5767168);
    } else if (i < 7077888) {
        // packed-spectrum forward DFT matrix (bf16), 4 elems per item.
        // col0 = Re F_0; odd n -> Re F_{(n+1)/2}; even n>0 -> Im F_{n/2};
        // numpy rfft: F_f = sum_k v_k e^{-2pi i f k /1024}.
        int g4 = i - 6815744;
        int idx = g4 << 2;
        int n = idx >> 10, k0 = idx & 1023;
        int f  = (n == 0) ? 0 : ((n & 1) ? ((n + 1) >> 1) : (n >> 1));
        bool re = (n == 0) || (n & 1);
        ushort4 o;
        u16* po = (u16*)&o;
#pragma unroll
        for (int j = 0; j < 4; ++j) {
            int r = (f * (k0 + j)) & 1023;
            float ang = (float)r * 6.1359233e-3f;   // 2*pi/1024
            float v = re ? __cosf(ang) : -__sinf(ang);
            po[j] = f2b(v);
        }
        ((ushort4*)fwdP)[g4] = o;
    } else if (i < 7340032) {
        // irfft: v_d = (1/1024)[F_0 + (-1)^d Re F_512
        //               + 2*sum_{f=1}^{511}(Re F_f cos - Im F_f sin)]
        int g4 = i - 7077888;
        int idx = g4 << 2;
        int d = idx >> 10, n0 = idx & 1023;
        ushort4 o;
        u16* po = (u16*)&o;
#pragma unroll
        for (int j = 0; j < 4; ++j) {
            int n = n0 + j;
            int f  = (n == 0) ? 0 : ((n & 1) ? ((n + 1) >> 1) : (n >> 1));
            bool re = (n == 0) || (n & 1);
            int r = (f * d) & 1023;
            float ang = (float)r * 6.1359233e-3f;
            float c = (f == 0 || f == 512) ? (1.0f / 1024.0f) : (2.0f / 1024.0f);
            float v = re ? c * __cosf(ang) : -c * __sinf(ang);
            po[j] = f2b(v);
        }
        ((ushort4*)invP)[g4] = o;
    } else {
        int j = i - 7340032;   // < 1024 float4s = 4096 floats
        ((float4*)Sf)[j] = float4{0.f, 0.f, 0.f, 0.f};
    }
}

// ---------------- GEMM: C[m,n] = sum_k A[m,k]*B[n,k] ----------------
// m97 structure + XCD swizzle + XOR-swizzled LDS (bank-conflict-free, staged
// by permuting each lane's GLOBAL chunk so global_load_lds's fixed lane->slot
// mapping still lands contiguously; slot (r,c) holds global chunk c^(r&7)).
// HARNESS-PROVEN; MfmaUtil ~36% single = this structure's ceiling.
// DO NOT RESTRUCTURE (R2/R3/R4: 256^2/8-phase ports all 96-102us vs 81us).
// DO NOT DROP BELOW ~3 BLOCKS/CU (R9: 512-block W2 = 2/CU cost ~55us).
// z-BATCHING PROVEN for operand-sharing GEMMs (R10/R12: b3 = 32.9us/GEMM,
// MfmaUtil 48-49%, FETCH 78MB vs 3x87 — tail + HBM-refetch amortized).
#define BM 128
#define BN 128
#define BK 64
#define EPI_BF16            0  // bf16 store
#define EPI_BIAS_BF16       1  // bf16 store, + bias[n]
#define EPI_BIAS_RELU_BF16  2  // bf16 store, + bias[n], relu
#define EPI_BIAS_ADDB_F32   3  // f32 store,  + bias[n] + bf16 residual addp16[off]
#define EPI_ADD_F32         4  // f32 store,  + existing f32 Cout[off]
#define EPI_BIASOPT_BF16    5  // bf16 store, + (bias ? bias[n] : 0)

template <int EPI>
__device__ __forceinline__ void gemm_body(
    const u16* __restrict__ A, const u16* __restrict__ B, void* __restrict__ Cout,
    const float* __restrict__ bias, const u16* __restrict__ addp16,
    int K, int lda, int ldb, int ldc)
{
    __shared__ __align__(16) u16 As[BM * BK];
    __shared__ __align__(16) u16 Bs[BN * BK];
    const int tid = threadIdx.x;

    // XCD-aware swizzle over the x/y grid only (z-batched slices each keep
    // their own contiguous-band mapping; per-slice nb % 8 == 0 holds).
    int m0, n0;
    {
        const int id = blockIdx.y * gridDim.x + blockIdx.x;
        const int nb = gridDim.x * gridDim.y;
        if ((nb & 7) == 0) {
            const int per = nb >> 3;
            const int t = (id & 7) * per + (id >> 3);
            n0 = (t % gridDim.x) * BN;
            m0 = (t / gridDim.x) * BM;
        } else {
            n0 = blockIdx.x * BN;
            m0 = blockIdx.y * BM;
        }
    }

    const int w = tid >> 6, l = tid & 63;
    const int wm = (w >> 1) << 6, wn = (w & 1) << 6;
    const int tm = l & 15, quad = l >> 4;
    const int sw = (tm & 7) << 3;            // read-side XOR swizzle (in u16 elems)

    f32x4 acc[4][4] = {};

    const int sr = tid >> 3;
    const int sc = ((tid & 7) ^ (sr & 7)) << 3;   // staged-side swizzled global chunk
    const u16* Ag = A + (size_t)(m0 + sr) * lda;
    const u16* Bg = B + (size_t)(n0 + sr) * ldb;
    u16* Asl = As + tid * 8;
    u16* Bsl = Bs + tid * 8;
    const size_t a32 = (size_t)32 * lda, b32 = (size_t)32 * ldb;

    for (int k0 = 0; k0 < K; k0 += BK) {
#pragma unroll
        for (int i = 0; i < 4; ++i) {
            ld16(Ag + (size_t)i * a32 + k0 + sc, Asl + i * 2048);
            ld16(Bg + (size_t)i * b32 + k0 + sc, Bsl + i * 2048);
        }
        __syncthreads();
#pragma unroll
        for (int kk = 0; kk < BK; kk += 32) {
            bf16x8 af[4], bfr[4];
#pragma unroll
            for (int i = 0; i < 4; ++i)
                af[i] = *(const bf16x8*)(const void*)(As + (wm + i * 16 + tm) * BK + ((((kk >> 3) + quad) << 3) ^ sw));
#pragma unroll
            for (int j = 0; j < 4; ++j)
                bfr[j] = *(const bf16x8*)(const void*)(Bs + (wn + j * 16 + tm) * BK + ((((kk >> 3) + quad) << 3) ^ sw));
#pragma unroll
            for (int i = 0; i < 4; ++i)
#pragma unroll
                for (int j = 0; j < 4; ++j)
                    acc[i][j] = __builtin_amdgcn_mfma_f32_16x16x32_bf16(af[i], bfr[j], acc[i][j], 0, 0, 0);
        }
        __syncthreads();
    }

    // C/D layout: col=lane&15, row=quad*4+reg (m89/m91-verified)
#pragma unroll
    for (int i = 0; i < 4; ++i) {
        const int gmb = m0 + wm + i * 16 + quad * 4;
#pragma unroll
        for (int j = 0; j < 4; ++j) {
            const int gn = n0 + wn + j * 16 + tm;
            float bv = 0.f;
            if (EPI == EPI_BIAS_BF16 || EPI == EPI_BIAS_RELU_BF16 || EPI == EPI_BIAS_ADDB_F32)
                bv = bias[gn];
            if (EPI == EPI_BIASOPT_BF16)
                bv = bias ? bias[gn] : 0.f;
#pragma unroll
            for (int r = 0; r < 4; ++r) {
                size_t off = (size_t)(gmb + r) * ldc + gn;
                float v = acc[i][j][r] + bv;
                if (EPI == EPI_BIAS_ADDB_F32) v += b2f(addp16[off]);
                if (EPI == EPI_ADD_F32)       v += ((const float*)Cout)[off];
                if (EPI == EPI_BIAS_RELU_BF16) v = fmaxf(v, 0.f);
                if (EPI == EPI_BF16 || EPI == EPI_BIAS_BF16 || EPI == EPI_BIAS_RELU_BF16 ||
                    EPI == EPI_BIASOPT_BF16)
                    ((u16*)Cout)[off] = f2b(v);
                else
                    ((float*)Cout)[off] = v;
            }
        }
    }
}

template <int EPI>
__global__ __launch_bounds__(256, 3) void gemm_bt_k(
    const u16* __restrict__ A, const u16* __restrict__ B, void* __restrict__ Cout,
    const float* __restrict__ bias, const u16* __restrict__ addp16,
    int K, int lda, int ldb, int ldc)
{
    gemm_body<EPI>(A, B, Cout, bias, addp16, K, lda, ldb, ldc);
}

// z=3 batch sharing A=S1: {q-proj(+bq), k-proj(+bk), FTx(no bias)}.
__global__ __launch_bounds__(256, 3) void gemm_b3a_k(
    const u16* __restrict__ A,
    const u16* __restrict__ B0, const u16* __restrict__ B1, const u16* __restrict__ B2,
    u16* __restrict__ C0, u16* __restrict__ C1, u16* __restrict__ C2,
    const float* __restrict__ b0, const float* __restrict__ b1,
    int K, int lda, int ldb, int ldc)
{
    const int z = blockIdx.z;
    const u16*   B  = (z == 0) ? B0 : ((z == 1) ? B1 : B2);
    u16*         C  = (z == 0) ? C0 : ((z == 1) ? C1 : C2);
    const float* bi = (z == 0) ? b0 : ((z == 1) ? b1 : nullptr);
    gemm_body<EPI_BIASOPT_BF16>(A, B, C, bi, nullptr, K, lda, ldb, ldc);
}

// z=2 batch sharing B=fwdP: {FTk, FTq}.
__global__ __launch_bounds__(256, 3) void gemm_b2s_k(
    const u16* __restrict__ A0, const u16* __restrict__ A1,
    const u16* __restrict__ B,
    u16* __restrict__ C0, u16* __restrict__ C1,
    int K, int lda, int ldb, int ldc)
{
    const int z = blockIdx.z;
    const u16* A = z ? A1 : A0;
    u16*       C = z ? C1 : C0;
    gemm_body<EPI_BF16>(A, B, C, nullptr, nullptr, K, lda, ldb, ldc);
}

// ---------------- LayerNorm bf16 -> bf16 (may be in-place) ----------------
__global__ void ln_bf16_k(const u16* __restrict__ src, u16* __restrict__ dst,
                          const float* __restrict__ g, const float* __restrict__ be) {
    __shared__ float red[8];
    const int t = blockIdx.x, tid = threadIdx.x;
    ushort4 h = ((const ushort4*)(src + (size_t)t * DD))[tid];
    float4 v = { b2f(h.x), b2f(h.y), b2f(h.z), b2f(h.w) };
    float s  = v.x + v.y + v.z + v.w;
    float ss = v.x * v.x + v.y * v.y + v.z * v.z + v.w * v.w;
    block_red2(s, ss, red, tid);
    float mean = s * (1.f / 1024.f);
    float inv  = 1.0f / sqrtf(ss * (1.f / 1024.f) - mean * mean + 1e-5f);
    float4 gv = ((const float4*)g)[tid];
    float4 bv = ((const float4*)be)[tid];
    ushort4 o;
    o.x = f2b((v.x - mean) * inv * gv.x + bv.x);
    o.y = f2b((v.y - mean) * inv * gv.y + bv.y);
    o.z = f2b((v.z - mean) * inv * gv.z + bv.z);
    o.w = f2b((v.w - mean) * inv * gv.w + bv.w);
    ((ushort4*)(dst + (size_t)t * DD))[tid] = o;
}

// fused q/k LayerNorm: one dispatch, two in-place tensors
__global__ void ln2_bf16_k(u16* __restrict__ qb, u16* __restrict__ kb,
                           const float* __restrict__ gq, const float* __restrict__ beq,
                           const float* __restrict__ gk, const float* __restrict__ bek) {
    __shared__ float red[8];
    const int b = blockIdx.x, tid = threadIdx.x;
    u16* io         = (b < NT) ? qb : kb;
    const float* g  = (b < NT) ? gq : gk;
    const float* be = (b < NT) ? beq : bek;
    const int t = (b < NT) ? b : (b - NT);
    ushort4 h = ((const ushort4*)(io + (size_t)t * DD))[tid];
    float4 v = { b2f(h.x), b2f(h.y), b2f(h.z), b2f(h.w) };
    float s  = v.x + v.y + v.z + v.w;
    float ss = v.x * v.x + v.y * v.y + v.z * v.z + v.w * v.w;
    block_red2(s, ss, red, tid);
    float mean = s * (1.f / 1024.f);
    float inv  = 1.0f / sqrtf(ss * (1.f / 1024.f) - mean * mean + 1e-5f);
    float4 gv = ((const float4*)g)[tid];
    float4 bv = ((const float4*)be)[tid];
    ushort4 o;
    o.x = f2b((v.x - mean) * inv * gv.x + bv.x);
    o.y = f2b((v.y - mean) * inv * gv.y + bv.y);
    o.z = f2b((v.z - mean) * inv * gv.z + bv.z);
    o.w = f2b((v.w - mean) * inv * gv.w + bv.w);
    ((ushort4*)(io + (size_t)t * DD))[tid] = o;
}

// ---------------- final LN in place on d_out (f32) ----------------
__global__ void ln_out_k(float* __restrict__ io, const float* __restrict__ g,
                         const float* __restrict__ be) {
    __shared__ float red[8];
    const int t = blockIdx.x, tid = threadIdx.x;
    float4 v = ((const float4*)(io + (size_t)t * DD))[tid];
    float s  = v.x + v.y + v.z + v.w;
    float ss = v.x * v.x + v.y * v.y + v.z * v.z + v.w * v.w;
    block_red2(s, ss, red, tid);
    float mean = s * (1.f / 1024.f);
    float inv  = 1.0f / sqrtf(ss * (1.f / 1024.f) - mean * mean + 1e-5f);
    float4 gv = ((const float4*)g)[tid];
    float4 bv = ((const float4*)be)[tid];
    float4 o;
    o.x = (v.x - mean) * inv * gv.x + bv.x;
    o.y = (v.y - mean) * inv * gv.y + bv.y;
    o.z = (v.z - mean) * inv * gv.z + bv.z;
    o.w = (v.w - mean) * inv * gv.w + bv.w;
    ((float4*)(io + (size_t)t * DD))[tid] = o;
}

// ---------------- pw1: Sf[b] += Kf .* Xf  (packed spectra) ----------------
// PW1_TOK=16 (R5-proven): 1024 blocks = 4 waves/SIMD TLP. TOK=64 (R8)
// collapsed TLP to 1 wave/SIMD and regressed ~18us — latency-bound, not
// atomic-bound. Keep 16.
#define PW1_TOK 16
__global__ void pw1_k(const u16* __restrict__ FTx, const u16* __restrict__ FTk,
                      float* __restrict__ Sf) {
    const int tid = threadIdx.x;
    const int t0 = blockIdx.x * PW1_TOK;
    const int b = t0 >> 12;
    float a0 = 0.f;
    float ar1 = 0.f, ai1 = 0.f;
    float ar2 = 0.f, ai2 = 0.f;
    const int f1 = tid + 1, f2 = tid + 257;
    for (int it = 0; it < PW1_TOK; ++it) {
        const size_t ro = (size_t)(t0 + it) * DD;
        const u16* rx = FTx + ro;
        const u16* rk = FTk + ro;
        if (tid == 0) a0 += b2f(rk[0]) * b2f(rx[0]);
        {
            float xr = b2f(rx[2 * f1 - 1]), xi = b2f(rx[2 * f1]);
            float kr = b2f(rk[2 * f1 - 1]), ki = b2f(rk[2 * f1]);
            ar1 += kr * xr - ki * xi;
            ai1 += kr * xi + ki * xr;
        }
        if (f2 < 512) {
            float xr = b2f(rx[2 * f2 - 1]), xi = b2f(rx[2 * f2]);
            float kr = b2f(rk[2 * f2 - 1]), ki = b2f(rk[2 * f2]);
            ar2 += kr * xr - ki * xi;
            ai2 += kr * xi + ki * xr;
        } else {
            ar2 += b2f(rk[1023]) * b2f(rx[1023]);
        }
    }
    float* sb = Sf + (size_t)b * DD;
    if (tid == 0) atomicAdd(&sb[0], a0);
    atomicAdd(&sb[2 * f1 - 1], ar1);
    atomicAdd(&sb[2 * f1],     ai1);
    if (f2 < 512) {
        atomicAdd(&sb[2 * f2 - 1], ar2);
        atomicAdd(&sb[2 * f2],     ai2);
    } else {
        atomicAdd(&sb[1023], ar2);
    }
}

// ---------------- pw2: G = Xf + Kf.*Xf + Sf.*conj(Qf), in-place over FTx ----------------
__global__ void pw2_k(u16* __restrict__ FTx, const u16* __restrict__ FTk,
                      const u16* __restrict__ FTq, const float* __restrict__ Sf) {
    const int t = blockIdx.x, tid = threadIdx.x;
    const int b = t >> 12;
    const size_t ro = (size_t)t * DD;
    u16* rx = FTx + ro;
    const u16* rk = FTk + ro;
    const u16* rq = FTq + ro;
    const float* sb = Sf + (size_t)b * DD;
    const int f1 = tid + 1, f2 = tid + 257;
    if (tid == 0) {
        float x = b2f(rx[0]), k = b2f(rk[0]), q = b2f(rq[0]);
        rx[0] = f2b(x + k * x + sb[0] * q);
    }
    {
        float xr = b2f(rx[2 * f1 - 1]), xi = b2f(rx[2 * f1]);
        float kr = b2f(rk[2 * f1 - 1]), ki = b2f(rk[2 * f1]);
        float qr = b2f(rq[2 * f1 - 1]), qi = b2f(rq[2 * f1]);
        float sr = sb[2 * f1 - 1], si = sb[2 * f1];
        rx[2 * f1 - 1] = f2b(xr + (kr * xr - ki * xi) + (sr * qr + si * qi));
        rx[2 * f1]     = f2b(xi + (kr * xi + ki * xr) + (si * qr - sr * qi));
    }
    if (f2 < 512) {
        float xr = b2f(rx[2 * f2 - 1]), xi = b2f(rx[2 * f2]);
        float kr = b2f(rk[2 * f2 - 1]), ki = b2f(rk[2 * f2]);
        float qr = b2f(rq[2 * f2 - 1]), qi = b2f(rq[2 * f2]);
        float sr = sb[2 * f2 - 1], si = sb[2 * f2];
        rx[2 * f2 - 1] = f2b(xr + (kr * xr - ki * xi) + (sr * qr + si * qi));
        rx[2 * f2]     = f2b(xi + (kr * xi + ki * xr) + (si * qr - sr * qi));
    } else {
        float x = b2f(rx[1023]), k = b2f(rk[1023]), q = b2f(rq[1023]);
        rx[1023] = f2b(x + k * x + sb[1023] * q);
    }
}

// ---------------- launch ----------------
extern "C" void kernel_launch(void* const* d_in, const int* in_sizes, int n_in,
                              void* d_out, int out_size, void* d_ws, size_t ws_size,
                              hipStream_t stream) {
    const float* x     = (const float*)d_in[0];
    const float* Wq    = (const float*)d_in[1];
    const float* bq    = (const float*)d_in[2];
    const float* gq    = (const float*)d_in[3];
    const float* betaq = (const float*)d_in[4];
    const float* Wk    = (const float*)d_in[5];
    const float* bk    = (const float*)d_in[6];
    const float* gk    = (const float*)d_in[7];
    const float* betak = (const float*)d_in[8];
    const float* g0    = (const float*)d_in[9];
    const float* beta0 = (const float*)d_in[10];
    const float* W1    = (const float*)d_in[11];
    const float* b1    = (const float*)d_in[12];
    const float* W2    = (const float*)d_in[13];
    const float* b2    = (const float*)d_in[14];
    const float* g1    = (const float*)d_in[15];
    const float* beta1 = (const float*)d_in[16];

    char* ws = (char*)d_ws;
    u16* S1 = (u16*)(ws + S1O);   // xb16 -> x1b
    u16* S2 = (u16*)(ws + S2O);   // qb -> T
    u16* S3 = (u16*)(ws + S3O);   // kb -> H chunk (S3..S4)
    u16* S4 = (u16*)(ws + S4O);   // FTx -> G
    u16* wq16 = (u16*)(ws + O_WQ);
    u16* wk16 = (u16*)(ws + O_WK);
    u16* w116 = (u16*)(ws + O_W1);
    u16* w216 = (u16*)(ws + O_W2);
    u16* fwdP = (u16*)(ws + O_FWD);
    u16* invP = (u16*)(ws + O_INV);
    float* Sf = (float*)(ws + O_SF);
    float* out = (float*)d_out;
    u16* O16 = (u16*)d_out;       // d_out as bf16 scratch for FTk/FTq
    u16* O16h = O16 + (size_t)16777216;   // +32MB

    // consts: single consolidated prep dispatch (casts + DFT gens + Sf zero)
    prep_k<<<PREP_GRID, 256, 0, stream>>>(x, Wq, Wk, W1, W2,
                                          S1, wq16, wk16, w116, w216,
                                          fwdP, invP, Sf);

    // z=3 batch sharing A=S1: q-proj -> S2 (+bq), k-proj -> S3 (+bk),
    // FTx = S1·Fwd -> S4 (no bias; FTx never depended on the q/k LN).
    gemm_b3a_k<<<dim3(8, 128, 3), 256, 0, stream>>>(S1, wq16, wk16, fwdP,
                                                    S2, S3, S4, bq, bk,
                                                    1024, 1024, 1024, 1024);
    // fused q/k LN in-place on S2/S3
    ln2_bf16_k<<<2 * NT, 256, 0, stream>>>(S2, S3, gq, betaq, gk, betak);

    // z=2 batch sharing B=fwdP: FTk = kb·Fwd -> O16, FTq = qb·Fwd -> O16h
    // (d_out as scratch; consumed by pw1/pw2 strictly before W2a overwrites).
    gemm_b2s_k<<<dim3(8, 128, 2), 256, 0, stream>>>(S3, S2, fwdP, O16, O16h,
                                                    1024, 1024, 1024, 1024);

    // freq-domain pointwise
    pw1_k<<<NT / PW1_TOK, 256, 0, stream>>>(S4, O16, Sf);
    pw2_k<<<NT, 256, 0, stream>>>(S4, O16, O16h, Sf);   // G in-place over FTx (S4)

    // inverse DFT: T = G @ Inv^T (bf16)
    gemm_bt_k<EPI_BF16><<<dim3(8, 128), 256, 0, stream>>>(S4, invP, S2, nullptr, nullptr, 1024, 1024, 1024, 1024);

    // x1 = LN(T) -> bf16
    ln_bf16_k<<<NT, 256, 0, stream>>>(S2, S1, g0, beta0);

    // FFN in two F-chunks of 2048 (R5-proven; M-chunked W2 at 512 blocks
    // regressed -55us in R9). H chunk lives in S3..S4 (64MB). W2a's full
    // 64MB f32 write also retires the FTk/FTq scratch in d_out.
    gemm_bt_k<EPI_BIAS_RELU_BF16><<<dim3(16, 128), 256, 0, stream>>>(S1, w116, S3, b1, nullptr, 1024, 1024, 1024, 2048);
    gemm_bt_k<EPI_BIAS_ADDB_F32><<<dim3(8, 128), 256, 0, stream>>>(S3, w216, out, b2, S1, 2048, 2048, 4096, 1024);
    gemm_bt_k<EPI_BIAS_RELU_BF16><<<dim3(16, 128), 256, 0, stream>>>(S1, w116 + (size_t)2048 * 1024, S3, b1 + 2048, nullptr, 1024, 1024, 1024, 2048);
    gemm_bt_k<EPI_ADD_F32><<<dim3(8, 128), 256, 0, stream>>>(S3, w216 + 2048, out, nullptr, nullptr, 2048, 2048, 4096, 1024);

    // final LN in place
    ln_out_k<<<NT, 256, 0, stream>>>(out, g1, beta1);

    (void)in_sizes; (void)n_in; (void)out_size; (void)ws_size;
}

// Round 16
// 767.059 us; speedup vs baseline: 1.0231x; 1.0060x over previous
//
#include <hip/hip_runtime.h>

typedef unsigned short u16;
typedef unsigned int   u32;
typedef __attribute__((ext_vector_type(8))) __bf16 bf16x8;
typedef __attribute__((ext_vector_type(4))) float   f32x4;

// ---------------- dims ----------------
#define NT   16384      // tokens = 4*4096
#define DD   1024
#define FFD  4096

// ---------------- ws layout (bytes), total ~152 MB ----------------
#define SREG  ((size_t)33554432)            // 32MB = 16384*1024*2
#define S1O   ((size_t)0)
#define S2O   (SREG)
#define S3O   (2*SREG)
#define S4O   (3*SREG)
#define O_WQ  (4*SREG)                      // 134,217,728
#define O_WK  (O_WQ + (size_t)2097152)
#define O_W1  (O_WK + (size_t)2097152)
#define O_W2  (O_W1 + (size_t)8388608)
#define O_FWD (O_W2 + (size_t)8388608)
#define O_INV (O_FWD + (size_t)2097152)
#define O_SF  (O_INV + (size_t)2097152)
// end = O_SF + 16384 = 159,399,936 bytes

// ---------------- helpers ----------------
__device__ __forceinline__ float b2f(u16 h) {
    u32 u = ((u32)h) << 16;
    return __uint_as_float(u);
}
__device__ __forceinline__ u16 f2b(float f) {  // RNE
    u32 u = __float_as_uint(f);
    u32 r = (u + 0x7FFFu + ((u >> 16) & 1u)) >> 16;
    return (u16)r;
}

__device__ __forceinline__ void ld16(const u16* g, u16* l) {
    __builtin_amdgcn_global_load_lds(
        (const __attribute__((address_space(1))) void*)g,
        (__attribute__((address_space(3))) void*)l, 16, 0, 0);
}

__device__ __forceinline__ void block_red2(float& a, float& b, float* red, int tid) {
#pragma unroll
    for (int off = 32; off; off >>= 1) {
        a += __shfl_down(a, off, 64);
        b += __shfl_down(b, off, 64);
    }
    int w = tid >> 6;
    if ((tid & 63) == 0) { red[w] = a; red[4 + w] = b; }
    __syncthreads();
    a = red[0] + red[1] + red[2] + red[3];
    b = red[4] + red[5] + red[6] + red[7];
}

// ---------------- consolidated prep kernel ----------------
// One range-partitioned grid replaces: zero_sf + 5 casts + gen_fwd + gen_inv.
//   [0, 4194304)                 x  (f32->bf16) -> S1
//   [4194304, 4456448)           Wq -> wq16
//   [4456448, 4718592)           Wk -> wk16
//   [4718592, 5767168)           W1 -> w116
//   [5767168, 6815744)           W2 -> w216
//   [6815744, 7077888)           gen fwdP (4 elems/item)
//   [7077888, 7340032)           gen invP (4 elems/item)
//   [7340032, 7341056)           Sf zero (float4)
#define PREP_ITEMS 7341056
#define PREP_GRID  28676          // * 256 = 7,341,056

__device__ __forceinline__ void cast4(const float* __restrict__ s, u16* __restrict__ d, int i) {
    float4 v = ((const float4*)s)[i];
    ushort4 o;
    o.x = f2b(v.x); o.y = f2b(v.y); o.z = f2b(v.z); o.w = f2b(v.w);
    ((ushort4*)d)[i] = o;
}

__global__ void prep_k(const float* __restrict__ x,  const float* __restrict__ Wq,
                       const float* __restrict__ Wk, const float* __restrict__ W1,
                       const float* __restrict__ W2,
                       u16* __restrict__ S1,   u16* __restrict__ wq16,
                       u16* __restrict__ wk16, u16* __restrict__ w116,
                       u16* __restrict__ w216, u16* __restrict__ fwdP,
                       u16* __restrict__ invP, float* __restrict__ Sf) {
    int i = blockIdx.x * 256 + threadIdx.x;
    if (i < 4194304) {
        cast4(x, S1, i);
    } else if (i < 4456448) {
        cast4(Wq, wq16, i - 4194304);
    } else if (i < 4718592) {
        cast4(Wk, wk16, i - 4456448);
    } else if (i < 5767168) {
        cast4(W1, w116, i - 4718592);
    } else if (i < 6815744) {
        cast4(W2, w216, i - 5767168);
    } else if (i < 7077888) {
        // packed-spectrum forward DFT matrix (bf16), 4 elems per item.
        // col0 = Re F_0; odd n -> Re F_{(n+1)/2}; even n>0 -> Im F_{n/2};
        // numpy rfft: F_f = sum_k v_k e^{-2pi i f k /1024}.
        int g4 = i - 6815744;
        int idx = g4 << 2;
        int n = idx >> 10, k0 = idx & 1023;
        int f  = (n == 0) ? 0 : ((n & 1) ? ((n + 1) >> 1) : (n >> 1));
        bool re = (n == 0) || (n & 1);
        ushort4 o;
        u16* po = (u16*)&o;
#pragma unroll
        for (int j = 0; j < 4; ++j) {
            int r = (f * (k0 + j)) & 1023;
            float ang = (float)r * 6.1359233e-3f;   // 2*pi/1024
            float v = re ? __cosf(ang) : -__sinf(ang);
            po[j] = f2b(v);
        }
        ((ushort4*)fwdP)[g4] = o;
    } else if (i < 7340032) {
        // irfft: v_d = (1/1024)[F_0 + (-1)^d Re F_512
        //               + 2*sum_{f=1}^{511}(Re F_f cos - Im F_f sin)]
        int g4 = i - 7077888;
        int idx = g4 << 2;
        int d = idx >> 10, n0 = idx & 1023;
        ushort4 o;
        u16* po = (u16*)&o;
#pragma unroll
        for (int j = 0; j < 4; ++j) {
            int n = n0 + j;
            int f  = (n == 0) ? 0 : ((n & 1) ? ((n + 1) >> 1) : (n >> 1));
            bool re = (n == 0) || (n & 1);
            int r = (f * d) & 1023;
            float ang = (float)r * 6.1359233e-3f;
            float c = (f == 0 || f == 512) ? (1.0f / 1024.0f) : (2.0f / 1024.0f);
            float v = re ? c * __cosf(ang) : -c * __sinf(ang);
            po[j] = f2b(v);
        }
        ((ushort4*)invP)[g4] = o;
    } else {
        int j = i - 7340032;   // < 1024 float4s = 4096 floats
        ((float4*)Sf)[j] = float4{0.f, 0.f, 0.f, 0.f};
    }
}

// ---------------- GEMM: C[m,n] = sum_k A[m,k]*B[n,k] ----------------
// m97 structure + XCD swizzle + XOR-swizzled LDS (bank-conflict-free, staged
// by permuting each lane's GLOBAL chunk so global_load_lds's fixed lane->slot
// mapping still lands contiguously; slot (r,c) holds global chunk c^(r&7)).
// HARNESS-PROVEN; MfmaUtil ~36% single = this structure's ceiling.
// DO NOT RESTRUCTURE (R2/R3/R4: 256^2/8-phase ports all 96-102us vs 81us).
// DO NOT DROP BELOW ~3 BLOCKS/CU (R9: 512-block W2 = 2/CU cost ~55us).
// z-BATCHING PROVEN for operand-sharing GEMMs (R10/R12/R13: 33-34us/GEMM,
// MfmaUtil 45-49%, FETCH amortized — tail + HBM-refetch amortized).
#define BM 128
#define BN 128
#define BK 64
#define EPI_BF16            0  // bf16 store
#define EPI_BIAS_BF16       1  // bf16 store, + bias[n]
#define EPI_BIAS_RELU_BF16  2  // bf16 store, + bias[n], relu
#define EPI_BIAS_ADDB_F32   3  // f32 store,  + bias[n] + bf16 residual addp16[off]
#define EPI_ADD_F32         4  // f32 store,  + existing f32 Cout[off]
#define EPI_BIASOPT_BF16    5  // bf16 store, + (bias ? bias[n] : 0)

template <int EPI>
__device__ __forceinline__ void gemm_body(
    const u16* __restrict__ A, const u16* __restrict__ B, void* __restrict__ Cout,
    const float* __restrict__ bias, const u16* __restrict__ addp16,
    int K, int lda, int ldb, int ldc)
{
    __shared__ __align__(16) u16 As[BM * BK];
    __shared__ __align__(16) u16 Bs[BN * BK];
    const int tid = threadIdx.x;

    // XCD-aware swizzle over the x/y grid only (z-batched slices each keep
    // their own contiguous-band mapping; per-slice nb % 8 == 0 holds).
    int m0, n0;
    {
        const int id = blockIdx.y * gridDim.x + blockIdx.x;
        const int nb = gridDim.x * gridDim.y;
        if ((nb & 7) == 0) {
            const int per = nb >> 3;
            const int t = (id & 7) * per + (id >> 3);
            n0 = (t % gridDim.x) * BN;
            m0 = (t / gridDim.x) * BM;
        } else {
            n0 = blockIdx.x * BN;
            m0 = blockIdx.y * BM;
        }
    }

    const int w = tid >> 6, l = tid & 63;
    const int wm = (w >> 1) << 6, wn = (w & 1) << 6;
    const int tm = l & 15, quad = l >> 4;
    const int sw = (tm & 7) << 3;            // read-side XOR swizzle (in u16 elems)

    f32x4 acc[4][4] = {};

    const int sr = tid >> 3;
    const int sc = ((tid & 7) ^ (sr & 7)) << 3;   // staged-side swizzled global chunk
    const u16* Ag = A + (size_t)(m0 + sr) * lda;
    const u16* Bg = B + (size_t)(n0 + sr) * ldb;
    u16* Asl = As + tid * 8;
    u16* Bsl = Bs + tid * 8;
    const size_t a32 = (size_t)32 * lda, b32 = (size_t)32 * ldb;

    for (int k0 = 0; k0 < K; k0 += BK) {
#pragma unroll
        for (int i = 0; i < 4; ++i) {
            ld16(Ag + (size_t)i * a32 + k0 + sc, Asl + i * 2048);
            ld16(Bg + (size_t)i * b32 + k0 + sc, Bsl + i * 2048);
        }
        __syncthreads();
#pragma unroll
        for (int kk = 0; kk < BK; kk += 32) {
            bf16x8 af[4], bfr[4];
#pragma unroll
            for (int i = 0; i < 4; ++i)
                af[i] = *(const bf16x8*)(const void*)(As + (wm + i * 16 + tm) * BK + ((((kk >> 3) + quad) << 3) ^ sw));
#pragma unroll
            for (int j = 0; j < 4; ++j)
                bfr[j] = *(const bf16x8*)(const void*)(Bs + (wn + j * 16 + tm) * BK + ((((kk >> 3) + quad) << 3) ^ sw));
#pragma unroll
            for (int i = 0; i < 4; ++i)
#pragma unroll
                for (int j = 0; j < 4; ++j)
                    acc[i][j] = __builtin_amdgcn_mfma_f32_16x16x32_bf16(af[i], bfr[j], acc[i][j], 0, 0, 0);
        }
        __syncthreads();
    }

    // C/D layout: col=lane&15, row=quad*4+reg (m89/m91-verified)
#pragma unroll
    for (int i = 0; i < 4; ++i) {
        const int gmb = m0 + wm + i * 16 + quad * 4;
#pragma unroll
        for (int j = 0; j < 4; ++j) {
            const int gn = n0 + wn + j * 16 + tm;
            float bv = 0.f;
            if (EPI == EPI_BIAS_BF16 || EPI == EPI_BIAS_RELU_BF16 || EPI == EPI_BIAS_ADDB_F32)
                bv = bias[gn];
            if (EPI == EPI_BIASOPT_BF16)
                bv = bias ? bias[gn] : 0.f;
#pragma unroll
            for (int r = 0; r < 4; ++r) {
                size_t off = (size_t)(gmb + r) * ldc + gn;
                float v = acc[i][j][r] + bv;
                if (EPI == EPI_BIAS_ADDB_F32) v += b2f(addp16[off]);
                if (EPI == EPI_ADD_F32)       v += ((const float*)Cout)[off];
                if (EPI == EPI_BIAS_RELU_BF16) v = fmaxf(v, 0.f);
                if (EPI == EPI_BF16 || EPI == EPI_BIAS_BF16 || EPI == EPI_BIAS_RELU_BF16 ||
                    EPI == EPI_BIASOPT_BF16)
                    ((u16*)Cout)[off] = f2b(v);
                else
                    ((float*)Cout)[off] = v;
            }
        }
    }
}

template <int EPI>
__global__ __launch_bounds__(256, 3) void gemm_bt_k(
    const u16* __restrict__ A, const u16* __restrict__ B, void* __restrict__ Cout,
    const float* __restrict__ bias, const u16* __restrict__ addp16,
    int K, int lda, int ldb, int ldc)
{
    gemm_body<EPI>(A, B, Cout, bias, addp16, K, lda, ldb, ldc);
}

// z=3 batch sharing A=S1: {q-proj(+bq), k-proj(+bk), FTx(no bias)}.
// R13-proven: 102us total (34/GEMM), MfmaUtil 45-46%.
__global__ __launch_bounds__(256, 3) void gemm_b3a_k(
    const u16* __restrict__ A,
    const u16* __restrict__ B0, const u16* __restrict__ B1, const u16* __restrict__ B2,
    u16* __restrict__ C0, u16* __restrict__ C1, u16* __restrict__ C2,
    const float* __restrict__ b0, const float* __restrict__ b1,
    int K, int lda, int ldb, int ldc)
{
    const int z = blockIdx.z;
    const u16*   B  = (z == 0) ? B0 : ((z == 1) ? B1 : B2);
    u16*         C  = (z == 0) ? C0 : ((z == 1) ? C1 : C2);
    const float* bi = (z == 0) ? b0 : ((z == 1) ? b1 : nullptr);
    gemm_body<EPI_BIASOPT_BF16>(A, B, C, bi, nullptr, K, lda, ldb, ldc);
}

// z=2 batch sharing B=fwdP: {FTk, FTq}.
__global__ __launch_bounds__(256, 3) void gemm_b2s_k(
    const u16* __restrict__ A0, const u16* __restrict__ A1,
    const u16* __restrict__ B,
    u16* __restrict__ C0, u16* __restrict__ C1,
    int K, int lda, int ldb, int ldc)
{
    const int z = blockIdx.z;
    const u16* A = z ? A1 : A0;
    u16*       C = z ? C1 : C0;
    gemm_body<EPI_BF16>(A, B, C, nullptr, nullptr, K, lda, ldb, ldc);
}

// ---------------- LayerNorm bf16 -> bf16 (may be in-place) ----------------
__global__ void ln_bf16_k(const u16* __restrict__ src, u16* __restrict__ dst,
                          const float* __restrict__ g, const float* __restrict__ be) {
    __shared__ float red[8];
    const int t = blockIdx.x, tid = threadIdx.x;
    ushort4 h = ((const ushort4*)(src + (size_t)t * DD))[tid];
    float4 v = { b2f(h.x), b2f(h.y), b2f(h.z), b2f(h.w) };
    float s  = v.x + v.y + v.z + v.w;
    float ss = v.x * v.x + v.y * v.y + v.z * v.z + v.w * v.w;
    block_red2(s, ss, red, tid);
    float mean = s * (1.f / 1024.f);
    float inv  = 1.0f / sqrtf(ss * (1.f / 1024.f) - mean * mean + 1e-5f);
    float4 gv = ((const float4*)g)[tid];
    float4 bv = ((const float4*)be)[tid];
    ushort4 o;
    o.x = f2b((v.x - mean) * inv * gv.x + bv.x);
    o.y = f2b((v.y - mean) * inv * gv.y + bv.y);
    o.z = f2b((v.z - mean) * inv * gv.z + bv.z);
    o.w = f2b((v.w - mean) * inv * gv.w + bv.w);
    ((ushort4*)(dst + (size_t)t * DD))[tid] = o;
}

// fused q/k LayerNorm: one dispatch, two in-place tensors
__global__ void ln2_bf16_k(u16* __restrict__ qb, u16* __restrict__ kb,
                           const float* __restrict__ gq, const float* __restrict__ beq,
                           const float* __restrict__ gk, const float* __restrict__ bek) {
    __shared__ float red[8];
    const int b = blockIdx.x, tid = threadIdx.x;
    u16* io         = (b < NT) ? qb : kb;
    const float* g  = (b < NT) ? gq : gk;
    const float* be = (b < NT) ? beq : bek;
    const int t = (b < NT) ? b : (b - NT);
    ushort4 h = ((const ushort4*)(io + (size_t)t * DD))[tid];
    float4 v = { b2f(h.x), b2f(h.y), b2f(h.z), b2f(h.w) };
    float s  = v.x + v.y + v.z + v.w;
    float ss = v.x * v.x + v.y * v.y + v.z * v.z + v.w * v.w;
    block_red2(s, ss, red, tid);
    float mean = s * (1.f / 1024.f);
    float inv  = 1.0f / sqrtf(ss * (1.f / 1024.f) - mean * mean + 1e-5f);
    float4 gv = ((const float4*)g)[tid];
    float4 bv = ((const float4*)be)[tid];
    ushort4 o;
    o.x = f2b((v.x - mean) * inv * gv.x + bv.x);
    o.y = f2b((v.y - mean) * inv * gv.y + bv.y);
    o.z = f2b((v.z - mean) * inv * gv.z + bv.z);
    o.w = f2b((v.w - mean) * inv * gv.w + bv.w);
    ((ushort4*)(io + (size_t)t * DD))[tid] = o;
}

// ---------------- final LN in place on d_out (f32) ----------------
__global__ void ln_out_k(float* __restrict__ io, const float* __restrict__ g,
                         const float* __restrict__ be) {
    __shared__ float red[8];
    const int t = blockIdx.x, tid = threadIdx.x;
    float4 v = ((const float4*)(io + (size_t)t * DD))[tid];
    float s  = v.x + v.y + v.z + v.w;
    float ss = v.x * v.x + v.y * v.y + v.z * v.z + v.w * v.w;
    block_red2(s, ss, red, tid);
    float mean = s * (1.f / 1024.f);
    float inv  = 1.0f / sqrtf(ss * (1.f / 1024.f) - mean * mean + 1e-5f);
    float4 gv = ((const float4*)g)[tid];
    float4 bv = ((const float4*)be)[tid];
    float4 o;
    o.x = (v.x - mean) * inv * gv.x + bv.x;
    o.y = (v.y - mean) * inv * gv.y + bv.y;
    o.z = (v.z - mean) * inv * gv.z + bv.z;
    o.w = (v.w - mean) * inv * gv.w + bv.w;
    ((float4*)(io + (size_t)t * DD))[tid] = o;
}

// ---------------- pw1: Sf[b] += Kf .* Xf  (packed spectra) ----------------
// PW1_TOK=16 (R5-proven): 1024 blocks = 4 waves/SIMD TLP. TOK=64 (R8)
// collapsed TLP to 1 wave/SIMD and regressed ~18us — latency-bound, not
// atomic-bound. Keep 16.
#define PW1_TOK 16
__global__ void pw1_k(const u16* __restrict__ FTx, const u16* __restrict__ FTk,
                      float* __restrict__ Sf) {
    const int tid = threadIdx.x;
    const int t0 = blockIdx.x * PW1_TOK;
    const int b = t0 >> 12;
    float a0 = 0.f;
    float ar1 = 0.f, ai1 = 0.f;
    float ar2 = 0.f, ai2 = 0.f;
    const int f1 = tid + 1, f2 = tid + 257;
    for (int it = 0; it < PW1_TOK; ++it) {
        const size_t ro = (size_t)(t0 + it) * DD;
        const u16* rx = FTx + ro;
        const u16* rk = FTk + ro;
        if (tid == 0) a0 += b2f(rk[0]) * b2f(rx[0]);
        {
            float xr = b2f(rx[2 * f1 - 1]), xi = b2f(rx[2 * f1]);
            float kr = b2f(rk[2 * f1 - 1]), ki = b2f(rk[2 * f1]);
            ar1 += kr * xr - ki * xi;
            ai1 += kr * xi + ki * xr;
        }
        if (f2 < 512) {
            float xr = b2f(rx[2 * f2 - 1]), xi = b2f(rx[2 * f2]);
            float kr = b2f(rk[2 * f2 - 1]), ki = b2f(rk[2 * f2]);
            ar2 += kr * xr - ki * xi;
            ai2 += kr * xi + ki * xr;
        } else {
            ar2 += b2f(rk[1023]) * b2f(rx[1023]);
        }
    }
    float* sb = Sf + (size_t)b * DD;
    if (tid == 0) atomicAdd(&sb[0], a0);
    atomicAdd(&sb[2 * f1 - 1], ar1);
    atomicAdd(&sb[2 * f1],     ai1);
    if (f2 < 512) {
        atomicAdd(&sb[2 * f2 - 1], ar2);
        atomicAdd(&sb[2 * f2],     ai2);
    } else {
        atomicAdd(&sb[1023], ar2);
    }
}

// ---------------- pw2: G = Xf + Kf.*Xf + Sf.*conj(Qf), in-place over FTx ----------------
__global__ void pw2_k(u16* __restrict__ FTx, const u16* __restrict__ FTk,
                      const u16* __restrict__ FTq, const float* __restrict__ Sf) {
    const int t = blockIdx.x, tid = threadIdx.x;
    const int b = t >> 12;
    const size_t ro = (size_t)t * DD;
    u16* rx = FTx + ro;
    const u16* rk = FTk + ro;
    const u16* rq = FTq + ro;
    const float* sb = Sf + (size_t)b * DD;
    const int f1 = tid + 1, f2 = tid + 257;
    if (tid == 0) {
        float x = b2f(rx[0]), k = b2f(rk[0]), q = b2f(rq[0]);
        rx[0] = f2b(x + k * x + sb[0] * q);
    }
    {
        float xr = b2f(rx[2 * f1 - 1]), xi = b2f(rx[2 * f1]);
        float kr = b2f(rk[2 * f1 - 1]), ki = b2f(rk[2 * f1]);
        float qr = b2f(rq[2 * f1 - 1]), qi = b2f(rq[2 * f1]);
        float sr = sb[2 * f1 - 1], si = sb[2 * f1];
        rx[2 * f1 - 1] = f2b(xr + (kr * xr - ki * xi) + (sr * qr + si * qi));
        rx[2 * f1]     = f2b(xi + (kr * xi + ki * xr) + (si * qr - sr * qi));
    }
    if (f2 < 512) {
        float xr = b2f(rx[2 * f2 - 1]), xi = b2f(rx[2 * f2]);
        float kr = b2f(rk[2 * f2 - 1]), ki = b2f(rk[2 * f2]);
        float qr = b2f(rq[2 * f2 - 1]), qi = b2f(rq[2 * f2]);
        float sr = sb[2 * f2 - 1], si = sb[2 * f2];
        rx[2 * f2 - 1] = f2b(xr + (kr * xr - ki * xi) + (sr * qr + si * qi));
        rx[2 * f2]     = f2b(xi + (kr * xi + ki * xr) + (si * qr - sr * qi));
    } else {
        float x = b2f(rx[1023]), k = b2f(rk[1023]), q = b2f(rq[1023]);
        rx[1023] = f2b(x + k * x + sb[1023] * q);
    }
}

// ---------------- launch ----------------
extern "C" void kernel_launch(void* const* d_in, const int* in_sizes, int n_in,
                              void* d_out, int out_size, void* d_ws, size_t ws_size,
                              hipStream_t stream) {
    const float* x     = (const float*)d_in[0];
    const float* Wq    = (const float*)d_in[1];
    const float* bq    = (const float*)d_in[2];
    const float* gq    = (const float*)d_in[3];
    const float* betaq = (const float*)d_in[4];
    const float* Wk    = (const float*)d_in[5];
    const float* bk    = (const float*)d_in[6];
    const float* gk    = (const float*)d_in[7];
    const float* betak = (const float*)d_in[8];
    const float* g0    = (const float*)d_in[9];
    const float* beta0 = (const float*)d_in[10];
    const float* W1    = (const float*)d_in[11];
    const float* b1    = (const float*)d_in[12];
    const float* W2    = (const float*)d_in[13];
    const float* b2    = (const float*)d_in[14];
    const float* g1    = (const float*)d_in[15];
    const float* beta1 = (const float*)d_in[16];

    char* ws = (char*)d_ws;
    u16* S1 = (u16*)(ws + S1O);   // xb16 -> x1b
    u16* S2 = (u16*)(ws + S2O);   // qb -> T
    u16* S3 = (u16*)(ws + S3O);   // kb -> H chunk (S3..S4)
    u16* S4 = (u16*)(ws + S4O);   // FTx -> G
    u16* wq16 = (u16*)(ws + O_WQ);
    u16* wk16 = (u16*)(ws + O_WK);
    u16* w116 = (u16*)(ws + O_W1);
    u16* w216 = (u16*)(ws + O_W2);
    u16* fwdP = (u16*)(ws + O_FWD);
    u16* invP = (u16*)(ws + O_INV);
    float* Sf = (float*)(ws + O_SF);
    float* out = (float*)d_out;
    u16* O16 = (u16*)d_out;       // d_out as bf16 scratch for FTk/FTq
    u16* O16h = O16 + (size_t)16777216;   // +32MB

    // consts: single consolidated prep dispatch (casts + DFT gens + Sf zero)
    prep_k<<<PREP_GRID, 256, 0, stream>>>(x, Wq, Wk, W1, W2,
                                          S1, wq16, wk16, w116, w216,
                                          fwdP, invP, Sf);

    // z=3 batch sharing A=S1: q-proj -> S2 (+bq), k-proj -> S3 (+bk),
    // FTx = S1·Fwd -> S4 (no bias; FTx never depended on the q/k LN).
    gemm_b3a_k<<<dim3(8, 128, 3), 256, 0, stream>>>(S1, wq16, wk16, fwdP,
                                                    S2, S3, S4, bq, bk,
                                                    1024, 1024, 1024, 1024);
    // fused q/k LN in-place on S2/S3
    ln2_bf16_k<<<2 * NT, 256, 0, stream>>>(S2, S3, gq, betaq, gk, betak);

    // z=2 batch sharing B=fwdP: FTk = kb·Fwd -> O16, FTq = qb·Fwd -> O16h
    // (d_out as scratch; consumed by pw1/pw2 strictly before W2a overwrites).
    gemm_b2s_k<<<dim3(8, 128, 2), 256, 0, stream>>>(S3, S2, fwdP, O16, O16h,
                                                    1024, 1024, 1024, 1024);

    // freq-domain pointwise
    pw1_k<<<NT / PW1_TOK, 256, 0, stream>>>(S4, O16, Sf);
    pw2_k<<<NT, 256, 0, stream>>>(S4, O16, O16h, Sf);   // G in-place over FTx (S4)

    // inverse DFT: T = G @ Inv^T (bf16)
    gemm_bt_k<EPI_BF16><<<dim3(8, 128), 256, 0, stream>>>(S4, invP, S2, nullptr, nullptr, 1024, 1024, 1024, 1024);

    // x1 = LN(T) -> bf16
    ln_bf16_k<<<NT, 256, 0, stream>>>(S2, S1, g0, beta0);

    // FFN in two F-chunks of 2048 (R5-proven; M-chunked W2 at 512 blocks
    // regressed -55us in R9). H chunk lives in S3..S4 (64MB). W2a's full
    // 64MB f32 write also retires the FTk/FTq scratch in d_out.
    gemm_bt_k<EPI_BIAS_RELU_BF16><<<dim3(16, 128), 256, 0, stream>>>(S1, w116, S3, b1, nullptr, 1024, 1024, 1024, 2048);
    gemm_bt_k<EPI_BIAS_ADDB_F32><<<dim3(8, 128), 256, 0, stream>>>(S3, w216, out, b2, S1, 2048, 2048, 4096, 1024);
    gemm_bt_k<EPI_BIAS_RELU_BF16><<<dim3(16, 128), 256, 0, stream>>>(S1, w116 + (size_t)2048 * 1024, S3, b1 + 2048, nullptr, 1024, 1024, 1024, 2048);
    gemm_bt_k<EPI_ADD_F32><<<dim3(8, 128), 256, 0, stream>>>(S3, w216 + 2048, out, nullptr, nullptr, 2048, 2048, 4096, 1024);

    // final LN in place
    ln_out_k<<<NT, 256, 0, stream>>>(out, g1, beta1);

    (void)in_sizes; (void)n_in; (void)out_size; (void)ws_size;
}